// Round 1
// baseline (873.165 us; speedup 1.0000x reference)
//
#include <hip/hip_runtime.h>
#include <cfloat>

static __device__ __forceinline__ float lrelu(float v) { return v >= 0.f ? v : 0.2f * v; }

// ---------------- GEMM: C[M,N] = A[M,K] @ B[K,N] (+bias) (+relu) ----------------
// Requires: M%64==0, N%64==0, K%16==0, pointers 16B aligned.
__global__ __launch_bounds__(256) void gemm_k(const float* __restrict__ A,
                                              const float* __restrict__ B,
                                              const float* __restrict__ bias,
                                              float* __restrict__ C,
                                              int M, int K, int N, int relu)
{
    __shared__ float As[16][65];
    __shared__ float Bs[16][64];
    const int tid = threadIdx.x;
    const int tx = tid & 15, ty = tid >> 4;
    const int row0 = blockIdx.x * 64, col0 = blockIdx.y * 64;
    const int la_r = tid >> 2;          // 0..63 : tile row
    const int la_k = (tid & 3) << 2;    // 0,4,8,12
    const int lb_k = tid >> 4;          // 0..15
    const int lb_c = (tid & 15) << 2;   // 0..60
    float4 acc[4];
#pragma unroll
    for (int i = 0; i < 4; i++) acc[i] = make_float4(0.f, 0.f, 0.f, 0.f);

    for (int k0 = 0; k0 < K; k0 += 16) {
        float4 av = *reinterpret_cast<const float4*>(&A[(size_t)(row0 + la_r) * K + k0 + la_k]);
        float4 bv = *reinterpret_cast<const float4*>(&B[(size_t)(k0 + lb_k) * N + col0 + lb_c]);
        As[la_k + 0][la_r] = av.x;
        As[la_k + 1][la_r] = av.y;
        As[la_k + 2][la_r] = av.z;
        As[la_k + 3][la_r] = av.w;
        *reinterpret_cast<float4*>(&Bs[lb_k][lb_c]) = bv;
        __syncthreads();
#pragma unroll
        for (int kk = 0; kk < 16; kk++) {
            float4 b4 = *reinterpret_cast<const float4*>(&Bs[kk][tx << 2]);
            float a0 = As[kk][(ty << 2) + 0];
            float a1 = As[kk][(ty << 2) + 1];
            float a2 = As[kk][(ty << 2) + 2];
            float a3 = As[kk][(ty << 2) + 3];
            acc[0].x += a0 * b4.x; acc[0].y += a0 * b4.y; acc[0].z += a0 * b4.z; acc[0].w += a0 * b4.w;
            acc[1].x += a1 * b4.x; acc[1].y += a1 * b4.y; acc[1].z += a1 * b4.z; acc[1].w += a1 * b4.w;
            acc[2].x += a2 * b4.x; acc[2].y += a2 * b4.y; acc[2].z += a2 * b4.z; acc[2].w += a2 * b4.w;
            acc[3].x += a3 * b4.x; acc[3].y += a3 * b4.y; acc[3].z += a3 * b4.z; acc[3].w += a3 * b4.w;
        }
        __syncthreads();
    }
#pragma unroll
    for (int i = 0; i < 4; i++) {
        int r = row0 + (ty << 2) + i;
        int c = col0 + (tx << 2);
        float4 v = acc[i];
        if (bias) {
            float4 bb = *reinterpret_cast<const float4*>(&bias[c]);
            v.x += bb.x; v.y += bb.y; v.z += bb.z; v.w += bb.w;
        }
        if (relu) {
            v.x = fmaxf(v.x, 0.f); v.y = fmaxf(v.y, 0.f);
            v.z = fmaxf(v.z, 0.f); v.w = fmaxf(v.w, 0.f);
        }
        *reinterpret_cast<float4*>(&C[(size_t)r * N + c]) = v;
    }
}

// ---------------- per-(node,head) attention coefficients e_src, e_dst ----------------
__global__ __launch_bounds__(256) void escd_k(const float* __restrict__ H,
                                              const float* __restrict__ a_src,
                                              const float* __restrict__ a_dst,
                                              float* __restrict__ es, float* __restrict__ ed, int n)
{
    int wid = (int)((blockIdx.x * 256 + threadIdx.x) >> 6);
    int lane = threadIdx.x & 63;
    if (wid >= n * 3) return;
    int node = wid / 3, head = wid - node * 3;
    const float* hp = H + (size_t)node * 384 + head * 128;
    const float* aps = a_src + head * 128;
    const float* apd = a_dst + head * 128;
    float h0 = hp[lane], h1 = hp[lane + 64];
    float s = h0 * aps[lane] + h1 * aps[lane + 64];
    float d = h0 * apd[lane] + h1 * apd[lane + 64];
#pragma unroll
    for (int o = 32; o > 0; o >>= 1) { s += __shfl_down(s, o); d += __shfl_down(d, o); }
    if (lane == 0) { es[wid] = s; ed[wid] = d; }
}

// ---------------- CSR build ----------------
__global__ __launch_bounds__(256) void count_k(const int* __restrict__ dst,
                                               const int* __restrict__ valid,
                                               int* __restrict__ deg, int E)
{
    int e = blockIdx.x * 256 + threadIdx.x;
    if (e >= E) return;
    if (!valid || valid[e]) atomicAdd(&deg[dst[e]], 1);
}

__global__ __launch_bounds__(1024) void scan_k(const int* __restrict__ deg,
                                               int* __restrict__ off, int* __restrict__ cur, int n)
{
    __shared__ int part[1024];
    int t = threadIdx.x;
    int chunk = (n + 1023) >> 10;
    int b0 = t * chunk;
    int b1 = min(n, b0 + chunk);
    int s = 0;
    for (int i = b0; i < b1; i++) s += deg[i];
    part[t] = s;
    __syncthreads();
    for (int d = 1; d < 1024; d <<= 1) {
        int v = (t >= d) ? part[t - d] : 0;
        __syncthreads();
        part[t] += v;
        __syncthreads();
    }
    int excl = (t ? part[t - 1] : 0);
    for (int i = b0; i < b1; i++) { off[i] = excl; cur[i] = excl; excl += deg[i]; }
    if (t == 1023) off[n] = part[1023];
}

__global__ __launch_bounds__(256) void scatter_k(const int* __restrict__ dst,
                                                 const int* __restrict__ valid,
                                                 int* __restrict__ cur, int* __restrict__ csr, int E)
{
    int e = blockIdx.x * 256 + threadIdx.x;
    if (e >= E) return;
    if (!valid || valid[e]) {
        int p = atomicAdd(&cur[dst[e]], 1);
        csr[p] = e;
    }
}

// ---------------- GAT edge-softmax + aggregation (one wave per dst node) ----------------
__global__ __launch_bounds__(256) void gat_agg_k(const float* __restrict__ H,
                                                 const float* __restrict__ es,
                                                 const float* __restrict__ ed,
                                                 const int* __restrict__ roff,
                                                 const int* __restrict__ csr,
                                                 const int* __restrict__ srcArr,
                                                 const float* __restrict__ bias,
                                                 float* __restrict__ out, int n)
{
    int wid = (int)((blockIdx.x * 256 + threadIdx.x) >> 6);
    int lane = threadIdx.x & 63;
    if (wid >= n) return;
    const int d = wid;
    float edv[3], mx[3], selfl[3];
#pragma unroll
    for (int h = 0; h < 3; h++) {
        edv[h] = ed[(size_t)d * 3 + h];
        float l = lrelu(es[(size_t)d * 3 + h] + edv[h]);
        selfl[h] = l;
        mx[h] = l;
    }
    const int beg = roff[d], end = roff[d + 1];
    for (int e = beg; e < end; e++) {
        int s = srcArr[csr[e]];
#pragma unroll
        for (int h = 0; h < 3; h++) mx[h] = fmaxf(mx[h], lrelu(es[(size_t)s * 3 + h] + edv[h]));
    }
    float den[3];
#pragma unroll
    for (int h = 0; h < 3; h++) den[h] = expf(selfl[h] - mx[h]);
    for (int e = beg; e < end; e++) {
        int s = srcArr[csr[e]];
#pragma unroll
        for (int h = 0; h < 3; h++) den[h] += expf(lrelu(es[(size_t)s * 3 + h] + edv[h]) - mx[h]);
    }
    float inv[3], wsf[3];
#pragma unroll
    for (int h = 0; h < 3; h++) {
        inv[h] = 1.f / (den[h] + 1e-16f);
        wsf[h] = expf(selfl[h] - mx[h]) * inv[h];
    }
    float acc[6];
    const float* hp = H + (size_t)d * 384;
#pragma unroll
    for (int j = 0; j < 6; j++) acc[j] = wsf[j >> 1] * hp[lane + 64 * j];
    for (int e = beg; e < end; e++) {
        int s = srcArr[csr[e]];
        float w[3];
#pragma unroll
        for (int h = 0; h < 3; h++) w[h] = expf(lrelu(es[(size_t)s * 3 + h] + edv[h]) - mx[h]) * inv[h];
        const float* sp = H + (size_t)s * 384;
#pragma unroll
        for (int j = 0; j < 6; j++) acc[j] += w[j >> 1] * sp[lane + 64 * j];
    }
#pragma unroll
    for (int j = 0; j < 6; j++)
        out[(size_t)d * 384 + lane + 64 * j] = acc[j] + bias[lane + 64 * j];
}

// ---------------- TopK pooling score: tanh(x.w / ||w||)  (one wave per node) ----------------
__global__ __launch_bounds__(256) void score_k(const float* __restrict__ H,
                                               const float* __restrict__ w,
                                               float* __restrict__ sc, int n)
{
    int wid = (int)((blockIdx.x * 256 + threadIdx.x) >> 6);
    int lane = threadIdx.x & 63;
    if (wid >= n) return;
    float w0 = w[lane], w1 = w[lane + 64];
    const float* hp = H + (size_t)wid * 128;
    float s = hp[lane] * w0 + hp[lane + 64] * w1;
    float q = w0 * w0 + w1 * w1;
#pragma unroll
    for (int o = 32; o > 0; o >>= 1) { s += __shfl_down(s, o); q += __shfl_down(q, o); }
    if (lane == 0) sc[wid] = tanhf(s / sqrtf(q));
}

// ---------------- per-graph top-k selection (bitonic sort, desc score, asc idx tiebreak) ----------------
__global__ __launch_bounds__(512) void select_k(const float* __restrict__ sc,
                                                int per, int k,
                                                int* __restrict__ perm, float* __restrict__ ps,
                                                int* __restrict__ newid)
{
    __shared__ float s[512];
    __shared__ int id[512];
    const int b = blockIdx.x;
    const int t = threadIdx.x;
    const int P = blockDim.x;
    if (t < per) { s[t] = sc[(size_t)b * per + t]; id[t] = t; }
    else         { s[t] = -FLT_MAX; id[t] = per + t; }
    __syncthreads();
    for (int kk = 2; kk <= P; kk <<= 1)
        for (int j = kk >> 1; j > 0; j >>= 1) {
            int ixj = t ^ j;
            if (ixj > t) {
                float a = s[t], bq = s[ixj];
                int ia = id[t], ib = id[ixj];
                bool aBefore = (a > bq) || (a == bq && ia < ib);
                bool up = ((t & kk) == 0);
                if (up ? !aBefore : aBefore) { s[t] = bq; s[ixj] = a; id[t] = ib; id[ixj] = ia; }
            }
            __syncthreads();
        }
    if (t < k) {
        int og = b * per + id[t];
        int ng = b * k + t;
        perm[ng] = og;
        ps[ng] = s[t];
        newid[og] = ng;
    }
}

// ---------------- gated copy of kept nodes (one wave per new node) ----------------
__global__ __launch_bounds__(256) void gate_k(const float* __restrict__ H,
                                              const int* __restrict__ perm,
                                              const float* __restrict__ ps,
                                              float* __restrict__ X, int nNew)
{
    int wid = (int)((blockIdx.x * 256 + threadIdx.x) >> 6);
    int lane = threadIdx.x & 63;
    if (wid >= nNew) return;
    int o = perm[wid];
    float g = ps[wid];
    X[(size_t)wid * 128 + lane]      = H[(size_t)o * 128 + lane] * g;
    X[(size_t)wid * 128 + 64 + lane] = H[(size_t)o * 128 + 64 + lane] * g;
}

// ---------------- edge remap through pooling ----------------
__global__ __launch_bounds__(256) void remap_k(const int* __restrict__ s_old,
                                               const int* __restrict__ d_old,
                                               const int* __restrict__ v_old,
                                               const int* __restrict__ newid,
                                               int* __restrict__ s_new, int* __restrict__ d_new,
                                               int* __restrict__ v_new, int E)
{
    int e = blockIdx.x * 256 + threadIdx.x;
    if (e >= E) return;
    int v = v_old ? v_old[e] : 1;
    int ns = -1, nd = -1;
    if (v) { ns = newid[s_old[e]]; nd = newid[d_old[e]]; }
    int ok = (v && ns >= 0 && nd >= 0) ? 1 : 0;
    s_new[e] = ok ? ns : 0;
    d_new[e] = ok ? nd : 0;
    v_new[e] = ok;
}

// ---------------- global max+mean pool, accumulated into z ----------------
__global__ __launch_bounds__(128) void gpool_k(const float* __restrict__ X,
                                               float* __restrict__ z, int k)
{
    int b = blockIdx.x, c = threadIdx.x;
    const float* xp = X + (size_t)b * k * 128 + c;
    float mx = -FLT_MAX, sm = 0.f;
    for (int r = 0; r < k; r++) {
        float v = xp[(size_t)r * 128];
        mx = fmaxf(mx, v);
        sm += v;
    }
    z[b * 256 + c] += mx;
    z[b * 256 + 128 + c] += sm / (float)k;
}

extern "C" void kernel_launch(void* const* d_in, const int* in_sizes, int n_in,
                              void* d_out, int out_size, void* d_ws, size_t ws_size,
                              hipStream_t stream)
{
    (void)in_sizes; (void)n_in; (void)out_size; (void)ws_size;

    const float* x   = (const float*)d_in[0];
    const int*   ei  = (const int*)d_in[2];
    const float* W1  = (const float*)d_in[4];
    const float* as1 = (const float*)d_in[5];
    const float* ad1 = (const float*)d_in[6];
    const float* b1  = (const float*)d_in[7];
    const float* Wh1 = (const float*)d_in[8];
    const float* bh1 = (const float*)d_in[9];
    const float* pw1 = (const float*)d_in[10];
    const float* W2  = (const float*)d_in[11];
    const float* as2 = (const float*)d_in[12];
    const float* ad2 = (const float*)d_in[13];
    const float* b2  = (const float*)d_in[14];
    const float* Wh2 = (const float*)d_in[15];
    const float* bh2 = (const float*)d_in[16];
    const float* pw2 = (const float*)d_in[17];
    const float* W3  = (const float*)d_in[18];
    const float* as3 = (const float*)d_in[19];
    const float* ad3 = (const float*)d_in[20];
    const float* b3  = (const float*)d_in[21];
    const float* Wh3 = (const float*)d_in[22];
    const float* bh3 = (const float*)d_in[23];
    const float* pw3 = (const float*)d_in[24];
    const float* Wl1 = (const float*)d_in[25];
    const float* bl1 = (const float*)d_in[26];
    const float* Wl2 = (const float*)d_in[27];
    const float* bl2 = (const float*)d_in[28];
    float* out = (float*)d_out;

    const int E = 131072;
    const int n1 = 32768, per1 = 512, k1 = 410;
    const int n2 = 64 * k1, per2 = k1, k2 = 205;   // 26240, 410, 205
    const int n3 = 64 * k2, per3 = k2, k3 = 41;    // 13120, 205, 41
    const int n4 = 64 * k3;                        // 2624

    // ---- workspace carve ----
    char* wsb = (char*)d_ws;
    size_t off = 0;
    auto alloc = [&](size_t bytes) -> void* {
        void* p = wsb + off;
        off += (bytes + 255) & ~(size_t)255;
        return p;
    };
    float* A    = (float*)alloc((size_t)n1 * 384 * 4);  // h_lin, later h2
    float* Bf   = (float*)alloc((size_t)n1 * 384 * 4);  // gat output
    float* ES   = (float*)alloc((size_t)n1 * 3 * 4);
    float* ED   = (float*)alloc((size_t)n1 * 3 * 4);
    float* SC   = (float*)alloc((size_t)n1 * 4);
    int*   DEG  = (int*)alloc((size_t)(n1 + 1) * 4);
    int*   OFFS = (int*)alloc((size_t)(n1 + 1) * 4);
    int*   CUR  = (int*)alloc((size_t)n1 * 4);
    int*   CSR  = (int*)alloc((size_t)E * 4);
    int*   SRCA = (int*)alloc((size_t)E * 4);
    int*   DSTA = (int*)alloc((size_t)E * 4);
    int*   VALA = (int*)alloc((size_t)E * 4);
    int*   SRCB = (int*)alloc((size_t)E * 4);
    int*   DSTB = (int*)alloc((size_t)E * 4);
    int*   VALB = (int*)alloc((size_t)E * 4);
    float* X1   = (float*)alloc((size_t)n2 * 128 * 4);
    float* X2   = (float*)alloc((size_t)n3 * 128 * 4);
    float* X3   = (float*)alloc((size_t)n4 * 128 * 4);
    int*   PERM = (int*)alloc((size_t)n2 * 4);
    float* PSC  = (float*)alloc((size_t)n2 * 4);
    int*   NEWID= (int*)alloc((size_t)n1 * 4);
    float* Z    = (float*)alloc((size_t)64 * 256 * 4);
    float* ZH   = (float*)alloc((size_t)64 * 512 * 4);

    auto layer = [&](const float* xin, int n,
                     const int* src, const int* dst, const int* val,
                     const float* W, const float* as_, const float* ad_, const float* bb,
                     const float* Wh, const float* bh, const float* pw,
                     int per, int kk, float* Xn, int nNew,
                     int* srcN, int* dstN, int* valN)
    {
        gemm_k<<<dim3(n / 64, 384 / 64), 256, 0, stream>>>(xin, W, nullptr, A, n, 128, 384, 0);
        escd_k<<<(n * 3) / 4, 256, 0, stream>>>(A, as_, ad_, ES, ED, n);
        hipMemsetAsync(DEG, 0, (size_t)n * 4, stream);
        count_k<<<E / 256, 256, 0, stream>>>(dst, val, DEG, E);
        scan_k<<<1, 1024, 0, stream>>>(DEG, OFFS, CUR, n);
        scatter_k<<<E / 256, 256, 0, stream>>>(dst, val, CUR, CSR, E);
        gat_agg_k<<<n / 4, 256, 0, stream>>>(A, ES, ED, OFFS, CSR, src, bb, Bf, n);
        gemm_k<<<dim3(n / 64, 128 / 64), 256, 0, stream>>>(Bf, Wh, bh, A, n, 384, 128, 1);
        score_k<<<n / 4, 256, 0, stream>>>(A, pw, SC, n);
        hipMemsetAsync(NEWID, 0xFF, (size_t)n * 4, stream);
        int P2 = 1;
        while (P2 < per) P2 <<= 1;
        select_k<<<64, P2, 0, stream>>>(SC, per, kk, PERM, PSC, NEWID);
        gate_k<<<nNew / 4, 256, 0, stream>>>(A, PERM, PSC, Xn, nNew);
        if (srcN) remap_k<<<E / 256, 256, 0, stream>>>(src, dst, val, NEWID, srcN, dstN, valN, E);
        gpool_k<<<64, 128, 0, stream>>>(Xn, Z, kk);
    };

    hipMemsetAsync(Z, 0, (size_t)64 * 256 * 4, stream);

    layer(x,  n1, ei,   ei + E, nullptr, W1, as1, ad1, b1, Wh1, bh1, pw1, per1, k1, X1, n2, SRCA, DSTA, VALA);
    layer(X1, n2, SRCA, DSTA,   VALA,    W2, as2, ad2, b2, Wh2, bh2, pw2, per2, k2, X2, n3, SRCB, DSTB, VALB);
    layer(X2, n3, SRCB, DSTB,   VALB,    W3, as3, ad3, b3, Wh3, bh3, pw3, per3, k3, X3, n4, nullptr, nullptr, nullptr);

    gemm_k<<<dim3(1, 512 / 64), 256, 0, stream>>>(Z,  Wl1, bl1, ZH,  64, 256, 512, 1);
    gemm_k<<<dim3(1, 256 / 64), 256, 0, stream>>>(ZH, Wl2, bl2, out, 64, 512, 256, 0);
}

// Round 2
// 720.580 us; speedup vs baseline: 1.2118x; 1.2118x over previous
//
#include <hip/hip_runtime.h>
#include <cfloat>

static __device__ __forceinline__ float lrelu(float v) { return v >= 0.f ? v : 0.2f * v; }

// ---------------- GEMM: C[M,N] = A[M,K] @ B[K,N] (+bias) (+relu) ----------------
// Requires: M%64==0, N%64==0, K%16==0, pointers 16B aligned.
__global__ __launch_bounds__(256) void gemm_k(const float* __restrict__ A,
                                              const float* __restrict__ B,
                                              const float* __restrict__ bias,
                                              float* __restrict__ C,
                                              int M, int K, int N, int relu)
{
    __shared__ float As[16][65];
    __shared__ float Bs[16][64];
    const int tid = threadIdx.x;
    const int tx = tid & 15, ty = tid >> 4;
    const int row0 = blockIdx.x * 64, col0 = blockIdx.y * 64;
    const int la_r = tid >> 2;          // 0..63 : tile row
    const int la_k = (tid & 3) << 2;    // 0,4,8,12
    const int lb_k = tid >> 4;          // 0..15
    const int lb_c = (tid & 15) << 2;   // 0..60
    float4 acc[4];
#pragma unroll
    for (int i = 0; i < 4; i++) acc[i] = make_float4(0.f, 0.f, 0.f, 0.f);

    for (int k0 = 0; k0 < K; k0 += 16) {
        float4 av = *reinterpret_cast<const float4*>(&A[(size_t)(row0 + la_r) * K + k0 + la_k]);
        float4 bv = *reinterpret_cast<const float4*>(&B[(size_t)(k0 + lb_k) * N + col0 + lb_c]);
        As[la_k + 0][la_r] = av.x;
        As[la_k + 1][la_r] = av.y;
        As[la_k + 2][la_r] = av.z;
        As[la_k + 3][la_r] = av.w;
        *reinterpret_cast<float4*>(&Bs[lb_k][lb_c]) = bv;
        __syncthreads();
#pragma unroll
        for (int kk = 0; kk < 16; kk++) {
            float4 b4 = *reinterpret_cast<const float4*>(&Bs[kk][tx << 2]);
            float a0 = As[kk][(ty << 2) + 0];
            float a1 = As[kk][(ty << 2) + 1];
            float a2 = As[kk][(ty << 2) + 2];
            float a3 = As[kk][(ty << 2) + 3];
            acc[0].x += a0 * b4.x; acc[0].y += a0 * b4.y; acc[0].z += a0 * b4.z; acc[0].w += a0 * b4.w;
            acc[1].x += a1 * b4.x; acc[1].y += a1 * b4.y; acc[1].z += a1 * b4.z; acc[1].w += a1 * b4.w;
            acc[2].x += a2 * b4.x; acc[2].y += a2 * b4.y; acc[2].z += a2 * b4.z; acc[2].w += a2 * b4.w;
            acc[3].x += a3 * b4.x; acc[3].y += a3 * b4.y; acc[3].z += a3 * b4.z; acc[3].w += a3 * b4.w;
        }
        __syncthreads();
    }
#pragma unroll
    for (int i = 0; i < 4; i++) {
        int r = row0 + (ty << 2) + i;
        int c = col0 + (tx << 2);
        float4 v = acc[i];
        if (bias) {
            float4 bb = *reinterpret_cast<const float4*>(&bias[c]);
            v.x += bb.x; v.y += bb.y; v.z += bb.z; v.w += bb.w;
        }
        if (relu) {
            v.x = fmaxf(v.x, 0.f); v.y = fmaxf(v.y, 0.f);
            v.z = fmaxf(v.z, 0.f); v.w = fmaxf(v.w, 0.f);
        }
        *reinterpret_cast<float4*>(&C[(size_t)r * N + c]) = v;
    }
}

// ---------------- per-(node,head) attention coefficients e_src, e_dst ----------------
__global__ __launch_bounds__(256) void escd_k(const float* __restrict__ H,
                                              const float* __restrict__ a_src,
                                              const float* __restrict__ a_dst,
                                              float* __restrict__ es, float* __restrict__ ed, int n)
{
    int wid = (int)((blockIdx.x * 256 + threadIdx.x) >> 6);
    int lane = threadIdx.x & 63;
    if (wid >= n * 3) return;
    int node = wid / 3, head = wid - node * 3;
    const float* hp = H + (size_t)node * 384 + head * 128;
    const float* aps = a_src + head * 128;
    const float* apd = a_dst + head * 128;
    float h0 = hp[lane], h1 = hp[lane + 64];
    float s = h0 * aps[lane] + h1 * aps[lane + 64];
    float d = h0 * apd[lane] + h1 * apd[lane + 64];
#pragma unroll
    for (int o = 32; o > 0; o >>= 1) { s += __shfl_down(s, o); d += __shfl_down(d, o); }
    if (lane == 0) { es[wid] = s; ed[wid] = d; }
}

// ---------------- CSR build ----------------
__global__ __launch_bounds__(256) void count_k(const int* __restrict__ dst,
                                               const int* __restrict__ valid,
                                               int* __restrict__ deg, int E)
{
    int e = blockIdx.x * 256 + threadIdx.x;
    if (e >= E) return;
    if (!valid || valid[e]) atomicAdd(&deg[dst[e]], 1);
}

__global__ __launch_bounds__(1024) void scan_k(const int* __restrict__ deg,
                                               int* __restrict__ off, int* __restrict__ cur, int n)
{
    __shared__ int part[1024];
    int t = threadIdx.x;
    int chunk = (n + 1023) >> 10;
    int b0 = t * chunk;
    int b1 = min(n, b0 + chunk);
    int s = 0;
    for (int i = b0; i < b1; i++) s += deg[i];
    part[t] = s;
    __syncthreads();
    for (int d = 1; d < 1024; d <<= 1) {
        int v = (t >= d) ? part[t - d] : 0;
        __syncthreads();
        part[t] += v;
        __syncthreads();
    }
    int excl = (t ? part[t - 1] : 0);
    for (int i = b0; i < b1; i++) { off[i] = excl; cur[i] = excl; excl += deg[i]; }
    if (t == 1023) off[n] = part[1023];
}

__global__ __launch_bounds__(256) void scatter_k(const int* __restrict__ dst,
                                                 const int* __restrict__ valid,
                                                 int* __restrict__ cur, int* __restrict__ csr, int E)
{
    int e = blockIdx.x * 256 + threadIdx.x;
    if (e >= E) return;
    if (!valid || valid[e]) {
        int p = atomicAdd(&cur[dst[e]], 1);
        csr[p] = e;
    }
}

// ---------------- GAT edge-softmax + aggregation (one wave per dst node) ----------------
__global__ __launch_bounds__(256) void gat_agg_k(const float* __restrict__ H,
                                                 const float* __restrict__ es,
                                                 const float* __restrict__ ed,
                                                 const int* __restrict__ roff,
                                                 const int* __restrict__ csr,
                                                 const int* __restrict__ srcArr,
                                                 const float* __restrict__ bias,
                                                 float* __restrict__ out, int n)
{
    int wid = (int)((blockIdx.x * 256 + threadIdx.x) >> 6);
    int lane = threadIdx.x & 63;
    if (wid >= n) return;
    const int d = wid;
    float edv[3], mx[3], selfl[3];
#pragma unroll
    for (int h = 0; h < 3; h++) {
        edv[h] = ed[(size_t)d * 3 + h];
        float l = lrelu(es[(size_t)d * 3 + h] + edv[h]);
        selfl[h] = l;
        mx[h] = l;
    }
    const int beg = roff[d], end = roff[d + 1];
    for (int e = beg; e < end; e++) {
        int s = srcArr[csr[e]];
#pragma unroll
        for (int h = 0; h < 3; h++) mx[h] = fmaxf(mx[h], lrelu(es[(size_t)s * 3 + h] + edv[h]));
    }
    float den[3];
#pragma unroll
    for (int h = 0; h < 3; h++) den[h] = expf(selfl[h] - mx[h]);
    for (int e = beg; e < end; e++) {
        int s = srcArr[csr[e]];
#pragma unroll
        for (int h = 0; h < 3; h++) den[h] += expf(lrelu(es[(size_t)s * 3 + h] + edv[h]) - mx[h]);
    }
    float inv[3], wsf[3];
#pragma unroll
    for (int h = 0; h < 3; h++) {
        inv[h] = 1.f / (den[h] + 1e-16f);
        wsf[h] = expf(selfl[h] - mx[h]) * inv[h];
    }
    float acc[6];
    const float* hp = H + (size_t)d * 384;
#pragma unroll
    for (int j = 0; j < 6; j++) acc[j] = wsf[j >> 1] * hp[lane + 64 * j];
    for (int e = beg; e < end; e++) {
        int s = srcArr[csr[e]];
        float w[3];
#pragma unroll
        for (int h = 0; h < 3; h++) w[h] = expf(lrelu(es[(size_t)s * 3 + h] + edv[h]) - mx[h]) * inv[h];
        const float* sp = H + (size_t)s * 384;
#pragma unroll
        for (int j = 0; j < 6; j++) acc[j] += w[j >> 1] * sp[lane + 64 * j];
    }
#pragma unroll
    for (int j = 0; j < 6; j++)
        out[(size_t)d * 384 + lane + 64 * j] = acc[j] + bias[lane + 64 * j];
}

// ---------------- TopK pooling score: tanh(x.w / ||w||)  (one wave per node) ----------------
__global__ __launch_bounds__(256) void score_k(const float* __restrict__ H,
                                               const float* __restrict__ w,
                                               float* __restrict__ sc, int n)
{
    int wid = (int)((blockIdx.x * 256 + threadIdx.x) >> 6);
    int lane = threadIdx.x & 63;
    if (wid >= n) return;
    float w0 = w[lane], w1 = w[lane + 64];
    const float* hp = H + (size_t)wid * 128;
    float s = hp[lane] * w0 + hp[lane + 64] * w1;
    float q = w0 * w0 + w1 * w1;
#pragma unroll
    for (int o = 32; o > 0; o >>= 1) { s += __shfl_down(s, o); q += __shfl_down(q, o); }
    if (lane == 0) sc[wid] = tanhf(s / sqrtf(q));
}

// ---------------- per-graph top-k selection (bitonic sort, desc score, asc idx tiebreak) ----------------
__global__ __launch_bounds__(512) void select_k(const float* __restrict__ sc,
                                                int per, int k,
                                                int* __restrict__ perm, float* __restrict__ ps,
                                                int* __restrict__ newid)
{
    __shared__ float s[512];
    __shared__ int id[512];
    const int b = blockIdx.x;
    const int t = threadIdx.x;
    const int P = blockDim.x;
    if (t < per) { s[t] = sc[(size_t)b * per + t]; id[t] = t; }
    else         { s[t] = -FLT_MAX; id[t] = per + t; }
    __syncthreads();
    for (int kk = 2; kk <= P; kk <<= 1)
        for (int j = kk >> 1; j > 0; j >>= 1) {
            int ixj = t ^ j;
            if (ixj > t) {
                float a = s[t], bq = s[ixj];
                int ia = id[t], ib = id[ixj];
                bool aBefore = (a > bq) || (a == bq && ia < ib);
                bool up = ((t & kk) == 0);
                if (up ? !aBefore : aBefore) { s[t] = bq; s[ixj] = a; id[t] = ib; id[ixj] = ia; }
            }
            __syncthreads();
        }
    if (t < k) {
        int og = b * per + id[t];
        int ng = b * k + t;
        perm[ng] = og;
        ps[ng] = s[t];
        newid[og] = ng;
    }
}

// ---------------- gated copy of kept nodes (one wave per new node) ----------------
__global__ __launch_bounds__(256) void gate_k(const float* __restrict__ H,
                                              const int* __restrict__ perm,
                                              const float* __restrict__ ps,
                                              float* __restrict__ X, int nNew)
{
    int wid = (int)((blockIdx.x * 256 + threadIdx.x) >> 6);
    int lane = threadIdx.x & 63;
    if (wid >= nNew) return;
    int o = perm[wid];
    float g = ps[wid];
    X[(size_t)wid * 128 + lane]      = H[(size_t)o * 128 + lane] * g;
    X[(size_t)wid * 128 + 64 + lane] = H[(size_t)o * 128 + 64 + lane] * g;
}

// ---------------- edge remap through pooling ----------------
__global__ __launch_bounds__(256) void remap_k(const int* __restrict__ s_old,
                                               const int* __restrict__ d_old,
                                               const int* __restrict__ v_old,
                                               const int* __restrict__ newid,
                                               int* __restrict__ s_new, int* __restrict__ d_new,
                                               int* __restrict__ v_new, int E)
{
    int e = blockIdx.x * 256 + threadIdx.x;
    if (e >= E) return;
    int v = v_old ? v_old[e] : 1;
    int ns = -1, nd = -1;
    if (v) { ns = newid[s_old[e]]; nd = newid[d_old[e]]; }
    int ok = (v && ns >= 0 && nd >= 0) ? 1 : 0;
    s_new[e] = ok ? ns : 0;
    d_new[e] = ok ? nd : 0;
    v_new[e] = ok;
}

// ---------------- global max+mean pool, accumulated into z ----------------
// 1 block per graph, 1024 threads = 8 rowgroups x 128 cols. Unrolled so 4
// independent row-loads are in flight per wave (latency-bound fix: was 128
// threads with a serial k-length dependent chain -> 107us; now ~<15us).
__global__ __launch_bounds__(1024) void gpool_k(const float* __restrict__ X,
                                                float* __restrict__ z, int k)
{
    __shared__ float smx[8][128];
    __shared__ float ssm[8][128];
    const int b = blockIdx.x;
    const int col = threadIdx.x & 127;
    const int rg = threadIdx.x >> 7;
    const float* xp = X + (size_t)b * k * 128 + col;
    float mx = -FLT_MAX, sm = 0.f;
    int r = rg;
#pragma unroll 4
    for (; r + 32 <= k; r += 32) {
        float v0 = xp[(size_t)(r + 0)  * 128];
        float v1 = xp[(size_t)(r + 8)  * 128];
        float v2 = xp[(size_t)(r + 16) * 128];
        float v3 = xp[(size_t)(r + 24) * 128];
        mx = fmaxf(fmaxf(fmaxf(mx, v0), fmaxf(v1, v2)), v3);
        sm += v0 + v1 + v2 + v3;
    }
    for (; r < k; r += 8) {
        float v = xp[(size_t)r * 128];
        mx = fmaxf(mx, v);
        sm += v;
    }
    smx[rg][col] = mx;
    ssm[rg][col] = sm;
    __syncthreads();
    if (rg == 0) {
#pragma unroll
        for (int i = 1; i < 8; i++) { mx = fmaxf(mx, smx[i][col]); sm += ssm[i][col]; }
        z[b * 256 + col] += mx;
        z[b * 256 + 128 + col] += sm / (float)k;
    }
}

extern "C" void kernel_launch(void* const* d_in, const int* in_sizes, int n_in,
                              void* d_out, int out_size, void* d_ws, size_t ws_size,
                              hipStream_t stream)
{
    (void)in_sizes; (void)n_in; (void)out_size; (void)ws_size;

    const float* x   = (const float*)d_in[0];
    const int*   ei  = (const int*)d_in[2];
    const float* W1  = (const float*)d_in[4];
    const float* as1 = (const float*)d_in[5];
    const float* ad1 = (const float*)d_in[6];
    const float* b1  = (const float*)d_in[7];
    const float* Wh1 = (const float*)d_in[8];
    const float* bh1 = (const float*)d_in[9];
    const float* pw1 = (const float*)d_in[10];
    const float* W2  = (const float*)d_in[11];
    const float* as2 = (const float*)d_in[12];
    const float* ad2 = (const float*)d_in[13];
    const float* b2  = (const float*)d_in[14];
    const float* Wh2 = (const float*)d_in[15];
    const float* bh2 = (const float*)d_in[16];
    const float* pw2 = (const float*)d_in[17];
    const float* W3  = (const float*)d_in[18];
    const float* as3 = (const float*)d_in[19];
    const float* ad3 = (const float*)d_in[20];
    const float* b3  = (const float*)d_in[21];
    const float* Wh3 = (const float*)d_in[22];
    const float* bh3 = (const float*)d_in[23];
    const float* pw3 = (const float*)d_in[24];
    const float* Wl1 = (const float*)d_in[25];
    const float* bl1 = (const float*)d_in[26];
    const float* Wl2 = (const float*)d_in[27];
    const float* bl2 = (const float*)d_in[28];
    float* out = (float*)d_out;

    const int E = 131072;
    const int n1 = 32768, per1 = 512, k1 = 410;
    const int n2 = 64 * k1, per2 = k1, k2 = 205;   // 26240, 410, 205
    const int n3 = 64 * k2, per3 = k2, k3 = 41;    // 13120, 205, 41
    const int n4 = 64 * k3;                        // 2624

    // ---- workspace carve ----
    char* wsb = (char*)d_ws;
    size_t off = 0;
    auto alloc = [&](size_t bytes) -> void* {
        void* p = wsb + off;
        off += (bytes + 255) & ~(size_t)255;
        return p;
    };
    float* A    = (float*)alloc((size_t)n1 * 384 * 4);  // h_lin, later h2
    float* Bf   = (float*)alloc((size_t)n1 * 384 * 4);  // gat output
    float* ES   = (float*)alloc((size_t)n1 * 3 * 4);
    float* ED   = (float*)alloc((size_t)n1 * 3 * 4);
    float* SC   = (float*)alloc((size_t)n1 * 4);
    int*   DEG  = (int*)alloc((size_t)(n1 + 1) * 4);
    int*   OFFS = (int*)alloc((size_t)(n1 + 1) * 4);
    int*   CUR  = (int*)alloc((size_t)n1 * 4);
    int*   CSR  = (int*)alloc((size_t)E * 4);
    int*   SRCA = (int*)alloc((size_t)E * 4);
    int*   DSTA = (int*)alloc((size_t)E * 4);
    int*   VALA = (int*)alloc((size_t)E * 4);
    int*   SRCB = (int*)alloc((size_t)E * 4);
    int*   DSTB = (int*)alloc((size_t)E * 4);
    int*   VALB = (int*)alloc((size_t)E * 4);
    float* X1   = (float*)alloc((size_t)n2 * 128 * 4);
    float* X2   = (float*)alloc((size_t)n3 * 128 * 4);
    float* X3   = (float*)alloc((size_t)n4 * 128 * 4);
    int*   PERM = (int*)alloc((size_t)n2 * 4);
    float* PSC  = (float*)alloc((size_t)n2 * 4);
    int*   NEWID= (int*)alloc((size_t)n1 * 4);
    float* Z    = (float*)alloc((size_t)64 * 256 * 4);
    float* ZH   = (float*)alloc((size_t)64 * 512 * 4);

    auto layer = [&](const float* xin, int n,
                     const int* src, const int* dst, const int* val,
                     const float* W, const float* as_, const float* ad_, const float* bb,
                     const float* Wh, const float* bh, const float* pw,
                     int per, int kk, float* Xn, int nNew,
                     int* srcN, int* dstN, int* valN)
    {
        gemm_k<<<dim3(n / 64, 384 / 64), 256, 0, stream>>>(xin, W, nullptr, A, n, 128, 384, 0);
        escd_k<<<(n * 3) / 4, 256, 0, stream>>>(A, as_, ad_, ES, ED, n);
        hipMemsetAsync(DEG, 0, (size_t)n * 4, stream);
        count_k<<<E / 256, 256, 0, stream>>>(dst, val, DEG, E);
        scan_k<<<1, 1024, 0, stream>>>(DEG, OFFS, CUR, n);
        scatter_k<<<E / 256, 256, 0, stream>>>(dst, val, CUR, CSR, E);
        gat_agg_k<<<n / 4, 256, 0, stream>>>(A, ES, ED, OFFS, CSR, src, bb, Bf, n);
        gemm_k<<<dim3(n / 64, 128 / 64), 256, 0, stream>>>(Bf, Wh, bh, A, n, 384, 128, 1);
        score_k<<<n / 4, 256, 0, stream>>>(A, pw, SC, n);
        hipMemsetAsync(NEWID, 0xFF, (size_t)n * 4, stream);
        int P2 = 1;
        while (P2 < per) P2 <<= 1;
        select_k<<<64, P2, 0, stream>>>(SC, per, kk, PERM, PSC, NEWID);
        gate_k<<<nNew / 4, 256, 0, stream>>>(A, PERM, PSC, Xn, nNew);
        if (srcN) remap_k<<<E / 256, 256, 0, stream>>>(src, dst, val, NEWID, srcN, dstN, valN, E);
        gpool_k<<<64, 1024, 0, stream>>>(Xn, Z, kk);
    };

    hipMemsetAsync(Z, 0, (size_t)64 * 256 * 4, stream);

    layer(x,  n1, ei,   ei + E, nullptr, W1, as1, ad1, b1, Wh1, bh1, pw1, per1, k1, X1, n2, SRCA, DSTA, VALA);
    layer(X1, n2, SRCA, DSTA,   VALA,    W2, as2, ad2, b2, Wh2, bh2, pw2, per2, k2, X2, n3, SRCB, DSTB, VALB);
    layer(X2, n3, SRCB, DSTB,   VALB,    W3, as3, ad3, b3, Wh3, bh3, pw3, per3, k3, X3, n4, nullptr, nullptr, nullptr);

    gemm_k<<<dim3(1, 512 / 64), 256, 0, stream>>>(Z,  Wl1, bl1, ZH,  64, 256, 512, 1);
    gemm_k<<<dim3(1, 256 / 64), 256, 0, stream>>>(ZH, Wl2, bl2, out, 64, 512, 256, 0);
}